// Round 1
// baseline (1244.887 us; speedup 1.0000x reference)
//
#include <hip/hip_runtime.h>
#include <math.h>

// Problem constants
#define BATCH 4
#define SEQ   4096
#define DIM   2048
#define DS    64
#define NF    4096
#define NR    2048
#define NT    2048
#define NTOT  8192          // NF+NR+NT
#define TOK   16384         // BATCH*SEQ

// ---------------------------------------------------------------------------
// K0: per-neuron reciprocal norm: scale[n] = 1/max(||emb_n||, 1e-12)
// ---------------------------------------------------------------------------
__global__ __launch_bounds__(256) void k_norm(const float* __restrict__ emb,
                                              float* __restrict__ scale) {
  int row  = blockIdx.x * 4 + (threadIdx.x >> 6);
  int lane = threadIdx.x & 63;
  float v  = emb[(size_t)row * DS + lane];
  float ss = v * v;
#pragma unroll
  for (int m = 32; m >= 1; m >>= 1) ss += __shfl_xor(ss, m, 64);
  if (lane == 0) scale[row] = 1.0f / fmaxf(sqrtf(ss), 1e-12f);
}

// ---------------------------------------------------------------------------
// K1: h = x @ W + b    (M=16384, K=2048, N=64)
// block: 64 tokens x 64 cols, K-tiles of 32. 256 threads.
// thread: cg=tid&7 -> cols c8..c8+7 ; tg=tid>>3 -> tokens {tg, tg+32}
// ---------------------------------------------------------------------------
__global__ __launch_bounds__(256) void k_h(const float* __restrict__ x,
                                           const float* __restrict__ W,
                                           const float* __restrict__ bias,
                                           float* __restrict__ h) {
  __shared__ float xs[64 * 36];   // [t][36] padded rows (36 f32)
  __shared__ float wt[32 * 64];   // [dd][c]
  const int tid = threadIdx.x;
  const int t0  = blockIdx.x * 64;
  const int cg  = tid & 7;
  const int tg  = tid >> 3;       // 0..31
  const int c8  = cg * 8;

  float acc[2][8];
#pragma unroll
  for (int j = 0; j < 2; ++j)
#pragma unroll
    for (int c = 0; c < 8; ++c) acc[j][c] = 0.0f;

  for (int d0 = 0; d0 < DIM; d0 += 32) {
    __syncthreads();
    // stage x tile: 64 tok x 32 d
#pragma unroll
    for (int k = 0; k < 2; ++k) {
      int idx = tid + k * 256;          // 0..511
      int t = idx >> 3, dd4 = idx & 7;
      float4 v = *reinterpret_cast<const float4*>(
          &x[(size_t)(t0 + t) * DIM + d0 + dd4 * 4]);
      *reinterpret_cast<float4*>(&xs[t * 36 + dd4 * 4]) = v;
    }
    // stage W tile: 32 d x 64 c
#pragma unroll
    for (int k = 0; k < 2; ++k) {
      int idx = tid + k * 256;
      int d = idx >> 4, cq = idx & 15;
      float4 v = *reinterpret_cast<const float4*>(
          &W[(size_t)(d0 + d) * DS + cq * 4]);
      *reinterpret_cast<float4*>(&wt[d * 64 + cq * 4]) = v;
    }
    __syncthreads();

#pragma unroll
    for (int dd4 = 0; dd4 < 8; ++dd4) {
      float4 xa4 = *reinterpret_cast<const float4*>(&xs[tg * 36 + dd4 * 4]);
      float4 xb4 = *reinterpret_cast<const float4*>(&xs[(tg + 32) * 36 + dd4 * 4]);
      float xa[4] = {xa4.x, xa4.y, xa4.z, xa4.w};
      float xb[4] = {xb4.x, xb4.y, xb4.z, xb4.w};
#pragma unroll
      for (int dd = 0; dd < 4; ++dd) {
        float4 w0 = *reinterpret_cast<const float4*>(&wt[(dd4 * 4 + dd) * 64 + c8]);
        float4 w1 = *reinterpret_cast<const float4*>(&wt[(dd4 * 4 + dd) * 64 + c8 + 4]);
        acc[0][0] += xa[dd] * w0.x;  acc[0][1] += xa[dd] * w0.y;
        acc[0][2] += xa[dd] * w0.z;  acc[0][3] += xa[dd] * w0.w;
        acc[0][4] += xa[dd] * w1.x;  acc[0][5] += xa[dd] * w1.y;
        acc[0][6] += xa[dd] * w1.z;  acc[0][7] += xa[dd] * w1.w;
        acc[1][0] += xb[dd] * w0.x;  acc[1][1] += xb[dd] * w0.y;
        acc[1][2] += xb[dd] * w0.z;  acc[1][3] += xb[dd] * w0.w;
        acc[1][4] += xb[dd] * w1.x;  acc[1][5] += xb[dd] * w1.y;
        acc[1][6] += xb[dd] * w1.z;  acc[1][7] += xb[dd] * w1.w;
      }
    }
  }

  float bl[8];
#pragma unroll
  for (int c = 0; c < 8; ++c) bl[c] = bias[c8 + c];
#pragma unroll
  for (int j = 0; j < 2; ++j) {
    int t = t0 + tg + 32 * j;
    float4 o0, o1;
    o0.x = acc[j][0] + bl[0]; o0.y = acc[j][1] + bl[1];
    o0.z = acc[j][2] + bl[2]; o0.w = acc[j][3] + bl[3];
    o1.x = acc[j][4] + bl[4]; o1.y = acc[j][5] + bl[5];
    o1.z = acc[j][6] + bl[6]; o1.w = acc[j][7] + bl[7];
    *reinterpret_cast<float4*>(&h[(size_t)t * DS + c8]) = o0;
    *reinterpret_cast<float4*>(&h[(size_t)t * DS + c8 + 4]) = o1;
  }
}

// ---------------------------------------------------------------------------
// K2 (phase A): partial softmax denominators.
// Zp[ch][t] = sum over neurons in chunk ch (1024 wide) of exp(h_t . emb_n * scale_n)
// thread <-> token (h in 64 VGPRs), neuron loop with wave-uniform emb reads.
// grid: (64 token-blocks, 8 chunks), block 256.
// ---------------------------------------------------------------------------
__global__ __launch_bounds__(256) void k_za(const float* __restrict__ h,
                                            const float* __restrict__ emb,
                                            const float* __restrict__ scale,
                                            float* __restrict__ Zp) {
  const int t  = blockIdx.x * 256 + threadIdx.x;
  const int ch = blockIdx.y;
  float hreg[64];
  const float4* hp = reinterpret_cast<const float4*>(&h[(size_t)t * DS]);
#pragma unroll
  for (int q = 0; q < 16; ++q) {
    float4 v = hp[q];
    hreg[4 * q + 0] = v.x; hreg[4 * q + 1] = v.y;
    hreg[4 * q + 2] = v.z; hreg[4 * q + 3] = v.w;
  }
  float Z = 0.0f;
  const int n0 = ch * 1024;
  for (int n = n0; n < n0 + 1024; ++n) {
    const float4* er = reinterpret_cast<const float4*>(&emb[(size_t)n * DS]);
    float l0 = 0.f, l1 = 0.f, l2 = 0.f, l3 = 0.f;
#pragma unroll
    for (int q = 0; q < 16; ++q) {
      float4 e = er[q];
      l0 += hreg[4 * q + 0] * e.x;
      l1 += hreg[4 * q + 1] * e.y;
      l2 += hreg[4 * q + 2] * e.z;
      l3 += hreg[4 * q + 3] * e.w;
    }
    float l = ((l0 + l1) + (l2 + l3)) * scale[n];
    Z += __expf(l);
  }
  Zp[(size_t)ch * TOK + t] = Z;
}

// ---------------------------------------------------------------------------
// K3: combine chunk Z's into per-slice coefficients a[slice][t] = imp_t / Z_slice
// ---------------------------------------------------------------------------
__global__ __launch_bounds__(256) void k_a2(const float* __restrict__ Zp,
                                            const float* __restrict__ imp,
                                            float* __restrict__ a) {
  int t = blockIdx.x * 256 + threadIdx.x;
  float zf = Zp[t] + Zp[TOK + t] + Zp[2 * TOK + t] + Zp[3 * TOK + t];
  float zr = Zp[4 * TOK + t] + Zp[5 * TOK + t];
  float zt = Zp[6 * TOK + t] + Zp[7 * TOK + t];
  float im = imp[t];
  a[t]           = im / zf;
  a[TOK + t]     = im / zr;
  a[2 * TOK + t] = im / zt;
}

// ---------------------------------------------------------------------------
// K4 (phase B): pooled partials.
// thread <-> neuron (emb row pre-scaled in 64 VGPRs), token loop, register acc.
// Bp[(b*4+tb)*8192 + n] = sum over 1024 tokens of a[slice][t]*exp(dot)
// grid: (32 neuron-chunks, 4 token-blocks, 4 batches), block 256.
// ---------------------------------------------------------------------------
__global__ __launch_bounds__(256) void k_pool(const float* __restrict__ h,
                                              const float* __restrict__ emb,
                                              const float* __restrict__ scale,
                                              const float* __restrict__ a,
                                              float* __restrict__ Bp) {
  const int n  = blockIdx.x * 256 + threadIdx.x;   // 0..8191
  const int tb = blockIdx.y;                       // 0..3
  const int b  = blockIdx.z;                       // 0..3
  const int slice = (n < NF) ? 0 : ((n < NF + NR) ? 1 : 2);
  const float sc = scale[n];

  float ereg[64];
  const float4* ep = reinterpret_cast<const float4*>(&emb[(size_t)n * DS]);
#pragma unroll
  for (int q = 0; q < 16; ++q) {
    float4 v = ep[q];
    ereg[4 * q + 0] = v.x * sc; ereg[4 * q + 1] = v.y * sc;
    ereg[4 * q + 2] = v.z * sc; ereg[4 * q + 3] = v.w * sc;
  }

  const float* ap = a + (size_t)slice * TOK + b * SEQ + tb * 1024;
  const float* hp = h + (size_t)(b * SEQ + tb * 1024) * DS;

  float acc = 0.0f;
#pragma unroll 2
  for (int s = 0; s < 1024; ++s) {
    const float* hh = hp + s * DS;   // wave-uniform -> scalar loads
    float l0 = 0.f, l1 = 0.f, l2 = 0.f, l3 = 0.f;
#pragma unroll
    for (int d = 0; d < 64; d += 4) {
      l0 += hh[d]     * ereg[d];
      l1 += hh[d + 1] * ereg[d + 1];
      l2 += hh[d + 2] * ereg[d + 2];
      l3 += hh[d + 3] * ereg[d + 3];
    }
    acc += ap[s] * __expf((l0 + l1) + (l2 + l3));
  }
  Bp[((size_t)(b * 4 + tb)) * NTOT + n] = acc;
}

// ---------------------------------------------------------------------------
// K5: per (batch, slice) reduce partials, top-k, renormalize, scatter to out.
// grid 12 = b*3 + slice, block 256.
// slice 0: feat N=4096 K=8 -> out[0:4096]
// slice 1: rel  N=2048 K=4 -> out[4096:6144] AND out[6144:8192]
// slice 2: tran N=2048 K=6 -> out[8192:10240]
// ---------------------------------------------------------------------------
__global__ __launch_bounds__(256) void k_topk(const float* __restrict__ Bp,
                                              float* __restrict__ out) {
  __shared__ float p[4096];
  __shared__ float rv[256];
  __shared__ int   ri[256];
  __shared__ float vals[8];
  __shared__ int   idxs[8];
  __shared__ float s_inv;

  const int bid = blockIdx.x;
  const int b   = bid / 3;
  const int sl  = bid % 3;
  const int off = (sl == 0) ? 0 : ((sl == 1) ? NF : NF + NR);
  const int N   = (sl == 0) ? NF : NR;     // 4096 or 2048
  const int K   = (sl == 0) ? 8 : ((sl == 1) ? 4 : 6);
  const int tid = threadIdx.x;

  for (int i = tid; i < N; i += 256) {
    float v = 0.0f;
#pragma unroll
    for (int tb = 0; tb < 4; ++tb)
      v += Bp[((size_t)(b * 4 + tb)) * NTOT + off + i];
    p[i] = v;
  }
  __syncthreads();

  for (int k = 0; k < K; ++k) {
    float bv = -2.0f;
    int bi = 1 << 30;
    for (int i = tid; i < N; i += 256) {
      float v = p[i];
      if (v > bv) { bv = v; bi = i; }
    }
    rv[tid] = bv; ri[tid] = bi;
    __syncthreads();
    for (int st = 128; st > 0; st >>= 1) {
      if (tid < st) {
        float v2 = rv[tid + st]; int i2 = ri[tid + st];
        if (v2 > rv[tid] || (v2 == rv[tid] && i2 < ri[tid])) {
          rv[tid] = v2; ri[tid] = i2;
        }
      }
      __syncthreads();
    }
    if (tid == 0) {
      vals[k] = rv[0]; idxs[k] = ri[0];
      p[ri[0]] = -1.0f;       // pooled values are strictly positive
    }
    __syncthreads();
  }

  if (tid == 0) {
    float s = 0.0f;
    for (int k = 0; k < K; ++k) s += vals[k];
    s_inv = 1.0f / (s + 1e-8f);
  }
  __syncthreads();

  float* ob = out + (size_t)b * (NF + 2 * NR + NT);   // 10240 per batch
  if (sl == 0) {
    for (int i = tid; i < NF; i += 256) ob[i] = 0.0f;
  } else if (sl == 1) {
    for (int i = tid; i < NR; i += 256) { ob[NF + i] = 0.0f; ob[NF + NR + i] = 0.0f; }
  } else {
    for (int i = tid; i < NT; i += 256) ob[NF + 2 * NR + i] = 0.0f;
  }
  __syncthreads();
  if (tid < K) {
    float v = vals[tid] * s_inv;
    int ix = idxs[tid];
    if (sl == 0) {
      ob[ix] = v;
    } else if (sl == 1) {
      ob[NF + ix] = v;
      ob[NF + NR + ix] = v;
    } else {
      ob[NF + 2 * NR + ix] = v;
    }
  }
}

// ---------------------------------------------------------------------------
extern "C" void kernel_launch(void* const* d_in, const int* in_sizes, int n_in,
                              void* d_out, int out_size, void* d_ws, size_t ws_size,
                              hipStream_t stream) {
  const float* x    = (const float*)d_in[0];   // [B,S,D]
  const float* imp  = (const float*)d_in[1];   // [B,S]
  const float* W    = (const float*)d_in[2];   // [D,DS]
  const float* bias = (const float*)d_in[3];   // [DS]
  const float* emb  = (const float*)d_in[4];   // [NTOT,DS]
  float* out = (float*)d_out;
  float* ws  = (float*)d_ws;

  // workspace layout (floats)
  float* scale = ws;                       // 8192
  float* h     = scale + NTOT;             // 16384*64 = 1048576
  float* Zp    = h + (size_t)TOK * DS;     // 8*16384  = 131072
  float* a     = Zp + 8 * TOK;             // 3*16384  = 49152
  float* Bp    = a + 3 * TOK;              // 16*8192  = 131072
  size_t need  = (size_t)(NTOT + TOK * DS + 8 * TOK + 3 * TOK + 16 * NTOT) * sizeof(float);
  if (ws_size < need) return;  // ~5.5 MB required

  k_norm<<<NTOT / 4, 256, 0, stream>>>(emb, scale);
  k_h<<<TOK / 64, 256, 0, stream>>>(x, W, bias, h);
  k_za<<<dim3(TOK / 256, 8), 256, 0, stream>>>(h, emb, scale, Zp);
  k_a2<<<TOK / 256, 256, 0, stream>>>(Zp, imp, a);
  k_pool<<<dim3(NTOT / 256, 4, 4), 256, 0, stream>>>(h, emb, scale, a, Bp);
  k_topk<<<12, 256, 0, stream>>>(Bp, out);
}

// Round 2
// 544.924 us; speedup vs baseline: 2.2845x; 2.2845x over previous
//
#include <hip/hip_runtime.h>
#include <math.h>

// Problem constants
#define BATCH 4
#define SEQ   4096
#define DIM   2048
#define DS    64
#define NF    4096
#define NR    2048
#define NT    2048
#define NTOT  8192          // NF+NR+NT
#define TOK   16384         // BATCH*SEQ

static __device__ __forceinline__ unsigned short f2bf(float x) {
  unsigned int u = __float_as_uint(x);
  u += 0x7fffu + ((u >> 16) & 1u);       // round-to-nearest-even
  return (unsigned short)(u >> 16);
}
static __device__ __forceinline__ float bf2f(unsigned int lo16) {
  return __uint_as_float(lo16 << 16);
}

// ---------------------------------------------------------------------------
// K0: per-neuron reciprocal norm: scale[n] = 1/max(||emb_n||, 1e-12)
// ---------------------------------------------------------------------------
__global__ __launch_bounds__(256) void k_norm(const float* __restrict__ emb,
                                              float* __restrict__ scale) {
  int row  = blockIdx.x * 4 + (threadIdx.x >> 6);
  int lane = threadIdx.x & 63;
  float v  = emb[(size_t)row * DS + lane];
  float ss = v * v;
#pragma unroll
  for (int m = 32; m >= 1; m >>= 1) ss += __shfl_xor(ss, m, 64);
  if (lane == 0) scale[row] = 1.0f / fmaxf(sqrtf(ss), 1e-12f);
}

// ---------------------------------------------------------------------------
// K1: h = x @ W + b    (M=16384, K=2048, N=64)
// ---------------------------------------------------------------------------
__global__ __launch_bounds__(256) void k_h(const float* __restrict__ x,
                                           const float* __restrict__ W,
                                           const float* __restrict__ bias,
                                           float* __restrict__ h) {
  __shared__ float xs[64 * 36];   // [t][36] padded rows
  __shared__ float wt[32 * 64];   // [dd][c]
  const int tid = threadIdx.x;
  const int t0  = blockIdx.x * 64;
  const int cg  = tid & 7;
  const int tg  = tid >> 3;       // 0..31
  const int c8  = cg * 8;

  float acc[2][8];
#pragma unroll
  for (int j = 0; j < 2; ++j)
#pragma unroll
    for (int c = 0; c < 8; ++c) acc[j][c] = 0.0f;

  for (int d0 = 0; d0 < DIM; d0 += 32) {
    __syncthreads();
#pragma unroll
    for (int k = 0; k < 2; ++k) {
      int idx = tid + k * 256;
      int t = idx >> 3, dd4 = idx & 7;
      float4 v = *reinterpret_cast<const float4*>(
          &x[(size_t)(t0 + t) * DIM + d0 + dd4 * 4]);
      *reinterpret_cast<float4*>(&xs[t * 36 + dd4 * 4]) = v;
    }
#pragma unroll
    for (int k = 0; k < 2; ++k) {
      int idx = tid + k * 256;
      int d = idx >> 4, cq = idx & 15;
      float4 v = *reinterpret_cast<const float4*>(
          &W[(size_t)(d0 + d) * DS + cq * 4]);
      *reinterpret_cast<float4*>(&wt[d * 64 + cq * 4]) = v;
    }
    __syncthreads();

#pragma unroll
    for (int dd4 = 0; dd4 < 8; ++dd4) {
      float4 xa4 = *reinterpret_cast<const float4*>(&xs[tg * 36 + dd4 * 4]);
      float4 xb4 = *reinterpret_cast<const float4*>(&xs[(tg + 32) * 36 + dd4 * 4]);
      float xa[4] = {xa4.x, xa4.y, xa4.z, xa4.w};
      float xb[4] = {xb4.x, xb4.y, xb4.z, xb4.w};
#pragma unroll
      for (int dd = 0; dd < 4; ++dd) {
        float4 w0 = *reinterpret_cast<const float4*>(&wt[(dd4 * 4 + dd) * 64 + c8]);
        float4 w1 = *reinterpret_cast<const float4*>(&wt[(dd4 * 4 + dd) * 64 + c8 + 4]);
        acc[0][0] += xa[dd] * w0.x;  acc[0][1] += xa[dd] * w0.y;
        acc[0][2] += xa[dd] * w0.z;  acc[0][3] += xa[dd] * w0.w;
        acc[0][4] += xa[dd] * w1.x;  acc[0][5] += xa[dd] * w1.y;
        acc[0][6] += xa[dd] * w1.z;  acc[0][7] += xa[dd] * w1.w;
        acc[1][0] += xb[dd] * w0.x;  acc[1][1] += xb[dd] * w0.y;
        acc[1][2] += xb[dd] * w0.z;  acc[1][3] += xb[dd] * w0.w;
        acc[1][4] += xb[dd] * w1.x;  acc[1][5] += xb[dd] * w1.y;
        acc[1][6] += xb[dd] * w1.z;  acc[1][7] += xb[dd] * w1.w;
      }
    }
  }

  float bl[8];
#pragma unroll
  for (int c = 0; c < 8; ++c) bl[c] = bias[c8 + c];
#pragma unroll
  for (int j = 0; j < 2; ++j) {
    int t = t0 + tg + 32 * j;
    float4 o0, o1;
    o0.x = acc[j][0] + bl[0]; o0.y = acc[j][1] + bl[1];
    o0.z = acc[j][2] + bl[2]; o0.w = acc[j][3] + bl[3];
    o1.x = acc[j][4] + bl[4]; o1.y = acc[j][5] + bl[5];
    o1.z = acc[j][6] + bl[6]; o1.w = acc[j][7] + bl[7];
    *reinterpret_cast<float4*>(&h[(size_t)t * DS + c8]) = o0;
    *reinterpret_cast<float4*>(&h[(size_t)t * DS + c8 + 4]) = o1;
  }
}

// ---------------------------------------------------------------------------
// K2: tiled logits GEMM (16384 x 8192 x K=64) with fused epilogues.
// tile: 128 tokens x 128 neurons, 256 threads, 8x8 register blocking.
// LDS: both tiles staged transposed (k-major). emb pre-scaled by 1/||emb||.
// MODE 0: Zp[t][cb] = row-sum of exp(logits)           (per 128-neuron block)
// MODE 1: MODE 0 + store E = exp(logits) as bf16
// MODE 2: Bp[tb][n] = sum_i a[sl][t_i] * exp(logits)   (pooled partials)
// ---------------------------------------------------------------------------
template<int MODE>
__global__ __launch_bounds__(256) void k_logits(
    const float* __restrict__ h, const float* __restrict__ emb,
    const float* __restrict__ scale, const float* __restrict__ a,
    float* __restrict__ Zp, unsigned short* __restrict__ E,
    float* __restrict__ Bp) {
  __shared__ float hs[64 * 128];   // [k][token]
  __shared__ float es[64 * 128];   // [k][neuron]  (pre-scaled)
  const int tid = threadIdx.x;
  const int tb  = blockIdx.x;          // token block 0..127
  const int cb  = blockIdx.y;          // neuron block 0..63
  const int t0  = tb * 128;
  const int n0  = cb * 128;

  // stage both tiles, transposed
#pragma unroll
  for (int it = 0; it < 8; ++it) {
    int idx = tid + it * 256;          // 0..2047
    int r = idx >> 4, dq = idx & 15;
    float4 v = *reinterpret_cast<const float4*>(&h[(size_t)(t0 + r) * DS + dq * 4]);
    hs[(dq * 4 + 0) * 128 + r] = v.x;
    hs[(dq * 4 + 1) * 128 + r] = v.y;
    hs[(dq * 4 + 2) * 128 + r] = v.z;
    hs[(dq * 4 + 3) * 128 + r] = v.w;
    float sc = scale[n0 + r];
    float4 w = *reinterpret_cast<const float4*>(&emb[(size_t)(n0 + r) * DS + dq * 4]);
    es[(dq * 4 + 0) * 128 + r] = w.x * sc;
    es[(dq * 4 + 1) * 128 + r] = w.y * sc;
    es[(dq * 4 + 2) * 128 + r] = w.z * sc;
    es[(dq * 4 + 3) * 128 + r] = w.w * sc;
  }
  __syncthreads();

  const int tx = tid & 15;             // neuron groups
  const int ty = tid >> 4;             // token group
  float acc[8][8];
#pragma unroll
  for (int i = 0; i < 8; ++i)
#pragma unroll
    for (int j = 0; j < 8; ++j) acc[i][j] = 0.0f;

#pragma unroll 2
  for (int k = 0; k < 64; ++k) {
    const float* hr = &hs[k * 128 + ty * 8];
    const float* er = &es[k * 128 + tx * 4];
    float4 a0 = *reinterpret_cast<const float4*>(hr);
    float4 a1 = *reinterpret_cast<const float4*>(hr + 4);
    float4 b0 = *reinterpret_cast<const float4*>(er);
    float4 b1 = *reinterpret_cast<const float4*>(er + 64);
    float av[8] = {a0.x, a0.y, a0.z, a0.w, a1.x, a1.y, a1.z, a1.w};
    float bv[8] = {b0.x, b0.y, b0.z, b0.w, b1.x, b1.y, b1.z, b1.w};
#pragma unroll
    for (int i = 0; i < 8; ++i)
#pragma unroll
      for (int j = 0; j < 8; ++j) acc[i][j] = fmaf(av[i], bv[j], acc[i][j]);
  }
  // thread's neurons: col(j) = tx*4+j (j<4), 64+tx*4+j-4 (j>=4)

  if (MODE == 2) {
    const int sl = (cb < 32) ? 0 : ((cb < 48) ? 1 : 2);
    float av8[8];
#pragma unroll
    for (int i = 0; i < 8; ++i) av8[i] = a[(size_t)sl * TOK + t0 + ty * 8 + i];
    float cs[8];
#pragma unroll
    for (int j = 0; j < 8; ++j) {
      float s = 0.0f;
#pragma unroll
      for (int i = 0; i < 8; ++i) s = fmaf(av8[i], __expf(acc[i][j]), s);
      cs[j] = s;
    }
    __syncthreads();
    float* red = hs;                   // reuse as [16][128]
#pragma unroll
    for (int j = 0; j < 8; ++j) {
      int c = (j < 4) ? (tx * 4 + j) : (64 + tx * 4 + (j - 4));
      red[ty * 128 + c] = cs[j];
    }
    __syncthreads();
    if (tid < 128) {
      float v = 0.0f;
#pragma unroll
      for (int yy = 0; yy < 16; ++yy) v += red[yy * 128 + tid];
      Bp[(size_t)tb * NTOT + n0 + tid] = v;
    }
  } else {
    float rs[8];
#pragma unroll
    for (int i = 0; i < 8; ++i) {
      float s = 0.0f;
#pragma unroll
      for (int j = 0; j < 8; ++j) {
        acc[i][j] = __expf(acc[i][j]);
        s += acc[i][j];
      }
      rs[i] = s;
    }
#pragma unroll
    for (int m = 1; m < 16; m <<= 1)
#pragma unroll
      for (int i = 0; i < 8; ++i) rs[i] += __shfl_xor(rs[i], m, 64);
    if (tx == 0) {
#pragma unroll
      for (int i = 0; i < 8; ++i)
        Zp[(size_t)(t0 + ty * 8 + i) * 64 + cb] = rs[i];
    }
    if (MODE == 1) {
#pragma unroll
      for (int i = 0; i < 8; ++i) {
        size_t row = (size_t)(t0 + ty * 8 + i) * NTOT;
        uint2 w0, w1;
        w0.x = (unsigned)f2bf(acc[i][0]) | ((unsigned)f2bf(acc[i][1]) << 16);
        w0.y = (unsigned)f2bf(acc[i][2]) | ((unsigned)f2bf(acc[i][3]) << 16);
        w1.x = (unsigned)f2bf(acc[i][4]) | ((unsigned)f2bf(acc[i][5]) << 16);
        w1.y = (unsigned)f2bf(acc[i][6]) | ((unsigned)f2bf(acc[i][7]) << 16);
        *reinterpret_cast<uint2*>(&E[row + n0 + tx * 4]) = w0;
        *reinterpret_cast<uint2*>(&E[row + n0 + 64 + tx * 4]) = w1;
      }
    }
  }
}

// ---------------------------------------------------------------------------
// K3: combine 64 Zp partials per token into a[slice][t] = imp_t / Z_slice
// ---------------------------------------------------------------------------
__global__ __launch_bounds__(256) void k_a2(const float* __restrict__ Zp,
                                            const float* __restrict__ imp,
                                            float* __restrict__ a) {
  int t = blockIdx.x * 256 + threadIdx.x;
  const float4* zp = reinterpret_cast<const float4*>(&Zp[(size_t)t * 64]);
  float zf = 0.f, zr = 0.f, zt = 0.f;
#pragma unroll
  for (int q = 0; q < 8; ++q)  { float4 v = zp[q]; zf += (v.x + v.y) + (v.z + v.w); }
#pragma unroll
  for (int q = 8; q < 12; ++q) { float4 v = zp[q]; zr += (v.x + v.y) + (v.z + v.w); }
#pragma unroll
  for (int q = 12; q < 16; ++q){ float4 v = zp[q]; zt += (v.x + v.y) + (v.z + v.w); }
  float im = imp[t];
  a[t]           = im / zf;
  a[TOK + t]     = im / zr;
  a[2 * TOK + t] = im / zt;
}

// ---------------------------------------------------------------------------
// K4 (E-path): pooled partials from stored E. Streaming, memory-bound.
// grid (16 nblocks x 8 tchunks x 4 batches), 256 thr, 2 neurons/thread.
// ---------------------------------------------------------------------------
__global__ __launch_bounds__(256) void k_poolE(const unsigned short* __restrict__ E,
                                               const float* __restrict__ a,
                                               float* __restrict__ Bp) {
  const int nb = blockIdx.x;          // 0..15
  const int tb = blockIdx.y;          // 0..7
  const int b  = blockIdx.z;          // 0..3
  const int n2 = nb * 512 + threadIdx.x * 2;
  const int sl = (n2 < NF) ? 0 : ((n2 < NF + NR) ? 1 : 2);
  const float* ap = a + (size_t)sl * TOK + b * SEQ + tb * 512;
  const unsigned short* ep = E + (size_t)(b * SEQ + tb * 512) * NTOT + n2;
  float acc0 = 0.f, acc1 = 0.f;
#pragma unroll 4
  for (int s = 0; s < 512; ++s) {
    unsigned int w = *reinterpret_cast<const unsigned int*>(ep + (size_t)s * NTOT);
    float at = ap[s];
    acc0 = fmaf(at, bf2f(w & 0xffffu), acc0);
    acc1 = fmaf(at, bf2f(w >> 16), acc1);
  }
  float* o = Bp + (size_t)(b * 8 + tb) * NTOT + n2;
  o[0] = acc0; o[1] = acc1;
}

// ---------------------------------------------------------------------------
// K5: per (batch, slice): reduce G partials, top-k, renorm, scatter.
// ---------------------------------------------------------------------------
__global__ __launch_bounds__(256) void k_topk(const float* __restrict__ Bp,
                                              float* __restrict__ out, int G) {
  __shared__ float p[4096];
  __shared__ float rv[256];
  __shared__ int   ri[256];
  __shared__ float vals[8];
  __shared__ int   idxs[8];
  __shared__ float s_inv;

  const int bid = blockIdx.x;
  const int b   = bid / 3;
  const int sl  = bid % 3;
  const int off = (sl == 0) ? 0 : ((sl == 1) ? NF : NF + NR);
  const int N   = (sl == 0) ? NF : NR;
  const int K   = (sl == 0) ? 8 : ((sl == 1) ? 4 : 6);
  const int tid = threadIdx.x;

  for (int i = tid; i < N; i += 256) {
    float v = 0.0f;
    for (int g = 0; g < G; ++g)
      v += Bp[((size_t)(b * G + g)) * NTOT + off + i];
    p[i] = v;
  }
  __syncthreads();

  for (int k = 0; k < K; ++k) {
    float bv = -2.0f;
    int bi = 1 << 30;
    for (int i = tid; i < N; i += 256) {
      float v = p[i];
      if (v > bv) { bv = v; bi = i; }
    }
    rv[tid] = bv; ri[tid] = bi;
    __syncthreads();
    for (int st = 128; st > 0; st >>= 1) {
      if (tid < st) {
        float v2 = rv[tid + st]; int i2 = ri[tid + st];
        if (v2 > rv[tid] || (v2 == rv[tid] && i2 < ri[tid])) {
          rv[tid] = v2; ri[tid] = i2;
        }
      }
      __syncthreads();
    }
    if (tid == 0) {
      vals[k] = rv[0]; idxs[k] = ri[0];
      p[ri[0]] = -1.0f;
    }
    __syncthreads();
  }

  if (tid == 0) {
    float s = 0.0f;
    for (int k = 0; k < K; ++k) s += vals[k];
    s_inv = 1.0f / (s + 1e-8f);
  }
  __syncthreads();

  float* ob = out + (size_t)b * (NF + 2 * NR + NT);
  if (sl == 0) {
    for (int i = tid; i < NF; i += 256) ob[i] = 0.0f;
  } else if (sl == 1) {
    for (int i = tid; i < NR; i += 256) { ob[NF + i] = 0.0f; ob[NF + NR + i] = 0.0f; }
  } else {
    for (int i = tid; i < NT; i += 256) ob[NF + 2 * NR + i] = 0.0f;
  }
  __syncthreads();
  if (tid < K) {
    float v = vals[tid] * s_inv;
    int ix = idxs[tid];
    if (sl == 0) {
      ob[ix] = v;
    } else if (sl == 1) {
      ob[NF + ix] = v;
      ob[NF + NR + ix] = v;
    } else {
      ob[NF + 2 * NR + ix] = v;
    }
  }
}

// ---------------------------------------------------------------------------
extern "C" void kernel_launch(void* const* d_in, const int* in_sizes, int n_in,
                              void* d_out, int out_size, void* d_ws, size_t ws_size,
                              hipStream_t stream) {
  const float* x    = (const float*)d_in[0];   // [B,S,D]
  const float* imp  = (const float*)d_in[1];   // [B,S]
  const float* W    = (const float*)d_in[2];   // [D,DS]
  const float* bias = (const float*)d_in[3];   // [DS]
  const float* emb  = (const float*)d_in[4];   // [NTOT,DS]
  float* out = (float*)d_out;
  float* ws  = (float*)d_ws;

  // workspace layout (floats)
  float* scale = ws;                             // 8192
  float* h     = scale + NTOT;                   // TOK*64
  float* Zp    = h + (size_t)TOK * DS;           // TOK*64
  float* a     = Zp + (size_t)TOK * 64;          // 3*TOK
  float* Bp    = a + 3 * TOK;                    // 128*NTOT (max)
  unsigned short* E = (unsigned short*)(Bp + (size_t)128 * NTOT);

  size_t base_f    = (size_t)NTOT + (size_t)TOK * DS + (size_t)TOK * 64 +
                     3 * (size_t)TOK + (size_t)128 * NTOT;
  size_t need_base = base_f * sizeof(float);                       // ~12.8 MB
  size_t need_E    = need_base + (size_t)TOK * NTOT * 2;           // +268 MB
  if (ws_size < need_base) return;
  const bool useE = (ws_size >= need_E);

  k_norm<<<NTOT / 4, 256, 0, stream>>>(emb, scale);
  k_h<<<TOK / 64, 256, 0, stream>>>(x, W, bias, h);

  if (useE) {
    k_logits<1><<<dim3(128, 64), 256, 0, stream>>>(h, emb, scale, nullptr, Zp, E, nullptr);
    k_a2<<<TOK / 256, 256, 0, stream>>>(Zp, imp, a);
    k_poolE<<<dim3(16, 8, 4), 256, 0, stream>>>(E, a, Bp);
    k_topk<<<12, 256, 0, stream>>>(Bp, out, 8);
  } else {
    k_logits<0><<<dim3(128, 64), 256, 0, stream>>>(h, emb, scale, nullptr, Zp, nullptr, nullptr);
    k_a2<<<TOK / 256, 256, 0, stream>>>(Zp, imp, a);
    k_logits<2><<<dim3(128, 64), 256, 0, stream>>>(h, emb, scale, a, nullptr, nullptr, Bp);
    k_topk<<<12, 256, 0, stream>>>(Bp, out, 32);
  }
}